// Round 6
// baseline (186.953 us; speedup 1.0000x reference)
//
#include <hip/hip_runtime.h>

typedef __attribute__((ext_vector_type(8))) short short8;
typedef __attribute__((ext_vector_type(4))) float f32x4;
typedef __attribute__((ext_vector_type(16))) float f32x16;
typedef __attribute__((ext_vector_type(2))) unsigned int u32x2;
typedef __attribute__((ext_vector_type(4))) unsigned int u32x4;
typedef unsigned short u16;
typedef unsigned int u32;

#define MFMA16(a, b, c) __builtin_amdgcn_mfma_f32_16x16x32_bf16((a), (b), (c), 0, 0, 0)
#define MFMA32(a, b, c) __builtin_amdgcn_mfma_f32_32x32x16_bf16((a), (b), (c), 0, 0, 0)

#define BAR_VMEM() asm volatile("s_waitcnt vmcnt(0) lgkmcnt(0)\ns_barrier" ::: "memory")
#define BAR_LDS()  asm volatile("s_waitcnt lgkmcnt(0)\ns_barrier" ::: "memory")

#define BATCH 8
#define NTOK 4096
#define CDIM 256
#define CQK 32
#define LOG2E 1.4426950408889634f

__device__ __forceinline__ u16 f2bf(float f) {
  u32 u = __float_as_uint(f);
  return (u16)((u + 0x7FFFu + ((u >> 16) & 1u)) >> 16);
}
// pack two f32 -> two bf16 (round-half-up) in one u32: bf(a) | bf(b)<<16
__device__ __forceinline__ u32 pack2(float a, float b) {
  const u32 ua = __float_as_uint(a) + 0x8000u;
  const u32 ub = __float_as_uint(b) + 0x8000u;
#if __has_builtin(__builtin_amdgcn_perm)
  return __builtin_amdgcn_perm(ub, ua, 0x07060302u);  // {ua.b2,ua.b3,ub.b2,ub.b3}
#else
  return (ua >> 16) | (ub & 0xFFFF0000u);
#endif
}
__device__ __forceinline__ float fexp2(float x) {
#if __has_builtin(__builtin_amdgcn_exp2f)
  return __builtin_amdgcn_exp2f(x);
#else
  return exp2f(x);
#endif
}

// ---------------------------------------------------------------------------
// Kernel 0: weights -> MFMA B-fragment order + f32 bias.
// ---------------------------------------------------------------------------
__global__ void k_prep(const float* __restrict__ Wq, const float* __restrict__ bq,
                       const float* __restrict__ Wk, const float* __restrict__ bk,
                       const float* __restrict__ Wv, const float* __restrict__ bv,
                       u16* __restrict__ wtf, float* __restrict__ bias) {
  const int f = blockIdx.x;        // 0..159 = ct*8+ks
  const int L = threadIdx.x;       // 0..63
  const int ct = f >> 3, ks = f & 7;
  const int o = ct * 16 + (L & 15);
  const int ch = ks * 32 + (L >> 4) * 8;
  short8 v8;
#pragma unroll
  for (int jj = 0; jj < 8; jj++) {
    const int c = ch + jj;
    float v;
    if (o < 32)       v = Wq[c * CQK + o];
    else if (o < 64)  v = Wk[c * CQK + (o - 32)];
    else              v = Wv[c * CDIM + (o - 64)];
    v8[jj] = (short)f2bf(v);
  }
  *(short8*)(wtf + (size_t)f * 512 + L * 8) = v8;
  if (f == 0) {
    for (int i = L; i < 320; i += 64) {
      if (i < 32)      bias[i] = bq[i];
      else if (i < 64) bias[i] = bk[i - 32];
      else             bias[i] = bv[i - 64];
    }
  }
}

// ---------------------------------------------------------------------------
// Kernel 1: fused cvt+proj. K outputs pre-scaled by log2(e) (exp2 trick).
// V is emitted in FRAGMENT-LINEAR layout: for each (b, j-tile, cg, frag
// fi=ks*2+ct2) the exact 1 KB that k_attn's 64 lanes consume as one MFMA32
// B-fragment is stored contiguously (half-swap on channel bit3 baked in,
// matching the P-LDS half swizzle). k_attn then loads V global->reg fully
// coalesced with no LDS staging.
// Index: frag(b,jt,cg,fi) at ((b*64+jt)*4+cg)*8+fi, 512 u16 each; +lane*8.
// ---------------------------------------------------------------------------
__global__ __launch_bounds__(256, 2) void k_proj(
    const float* __restrict__ x, const u16* __restrict__ wtf,
    const float* __restrict__ bias,
    u16* __restrict__ q_ws, u16* __restrict__ k_ws, u16* __restrict__ vt_ws) {
  __shared__ u16 x_lds[64 * 264];
  __shared__ u16 vt_t[64 * 72];
  const int m0 = blockIdx.x * 64;
  const int tid = threadIdx.x;
  const int w = tid >> 6, L = tid & 63;
  const int lr = L & 15, q4 = L >> 4;

  // ks=0 weight prefetch (independent of LDS) — flies across the x staging.
  short8 wfA[5], wfB[5];
#pragma unroll
  for (int j = 0; j < 5; j++)
    wfA[j] = *(const short8*)(wtf + ((size_t)((j * 4 + w) * 8 + 0)) * 512 + L * 8);

  // stage + convert x tile via perm-packs
#pragma unroll
  for (int ii = 0; ii < 8; ii++) {
    const int e = (tid + 256 * ii) * 8;
    const int row = e >> 8, col = e & 255;
    const float* src = x + (size_t)(m0 + row) * CDIM + col;
    f32x4 a = *(const f32x4*)src;
    f32x4 b4 = *(const f32x4*)(src + 4);
    u32x4 pk;
    pk[0] = pack2(a[0], a[1]);
    pk[1] = pack2(a[2], a[3]);
    pk[2] = pack2(b4[0], b4[1]);
    pk[3] = pack2(b4[2], b4[3]);
    *(u32x4*)&x_lds[row * 264 + col] = pk;
  }
  __syncthreads();

  f32x4 acc[4][5];
#pragma unroll
  for (int rg = 0; rg < 4; rg++)
#pragma unroll
    for (int j = 0; j < 5; j++) acc[rg][j] = (f32x4){0.f, 0.f, 0.f, 0.f};

#pragma unroll
  for (int ks = 0; ks < 8; ks++) {
    // prefetch next ks-slice into the other buffer (no barriers in this loop)
    if (ks < 7) {
#pragma unroll
      for (int j = 0; j < 5; j++) {
        short8 v = *(const short8*)(wtf +
            ((size_t)((j * 4 + w) * 8 + ks + 1)) * 512 + L * 8);
        if (ks & 1) wfA[j] = v; else wfB[j] = v;
      }
    }
#pragma unroll
    for (int rg = 0; rg < 4; rg++) {
      short8 a = *(const short8*)&x_lds[(rg * 16 + lr) * 264 + ks * 32 + q4 * 8];
#pragma unroll
      for (int j = 0; j < 5; j++)
        acc[rg][j] = MFMA16(a, (ks & 1) ? wfB[j] : wfA[j], acc[rg][j]);
    }
  }

  // q/k epilogue (j=0 -> ct = w; k scaled by log2e). Branch is wave-uniform.
  {
    const float bb = bias[w * 16 + lr];
#pragma unroll
    for (int rg = 0; rg < 4; rg++)
#pragma unroll
      for (int r = 0; r < 4; r++) {
        const int row = m0 + rg * 16 + q4 * 4 + r;
        float v = acc[rg][0][r] + bb;
        if (w < 2) q_ws[(size_t)row * CQK + w * 16 + lr] = f2bf(v);
        else       k_ws[(size_t)row * CQK + (w - 2) * 16 + lr] = f2bf(v * LOG2E);
      }
  }
  // v epilogue: transpose via LDS with half-swap, then fragment-linear store.
  const int b = m0 >> 12, nt = (m0 & 4095) >> 6;
  const int rb2 = ((lr >> 3) & 1) << 2;       // row-bit3 of c_l = w*16+lr
  const int c_l = w * 16 + lr;
#pragma unroll
  for (int cg = 0; cg < 4; cg++) {
    __syncthreads();
    const int j = cg + 1;
    const float bb = bias[(4 + cg * 4 + w) * 16 + lr];
#pragma unroll
    for (int rg = 0; rg < 4; rg++) {
      const int n_base = (rg * 16 + q4 * 4) ^ rb2;  // half-swapped physical pos
      u32x2 pk;
      pk[0] = pack2(acc[rg][j][0] + bb, acc[rg][j][1] + bb);
      pk[1] = pack2(acc[rg][j][2] + bb, acc[rg][j][3] + bb);
      *(u32x2*)&vt_t[c_l * 72 + n_base] = pk;
    }
    __syncthreads();
    // fragment-linear store: consumer group == cg; frag fi = ks*2+ct2;
    // lane holds channel ct2*32+(lane&31), j-window (ks*2+(lane>>5))*8..+8.
#pragma unroll
    for (int i = 0; i < 2; i++) {
      const int gch = tid + 256 * i;
      const int fi = gch >> 6;            // 0..7
      const int lane = gch & 63;
      const int ks2 = fi >> 1, ct2 = fi & 1;
      short8 v = *(const short8*)&vt_t[(ct2 * 32 + (lane & 31)) * 72 +
                                       (ks2 * 2 + (lane >> 5)) * 8];
      *(short8*)(vt_ws +
          ((((size_t)(b * 64 + nt) * 4 + cg) * 8 + fi) * 512) + lane * 8) = v;
    }
  }
}

// ---------------------------------------------------------------------------
// Kernel 2: flash attention, 8-wave blocks (512 threads) for 16 waves/CU
// (4/SIMD, 2 independent barrier domains) — was 2 waves/SIMD in lockstep.
// Wave roles split finer: S^T: wave w owns (i-sub = w&3, j-half = w>>2):
// 2 MFMA16 + 2 P-subtile writes; row-sum is a j-half partial, merged via a
// 64-float LDS pass at the end. PV: wave w owns ch-block w*32..+31 x all 64
// i-rows: per ks one a_p pair read + 2 MFMA32 with V frags fi=ks*2+(w&1) of
// group w>>1 — V global traffic per block-iter unchanged (no duplication).
// V stays global->register (fragment-linear, coalesced); only P round-trips
// through LDS (double-buffered, LDS-only barrier in the hot loop).
// ---------------------------------------------------------------------------
__global__ __launch_bounds__(512, 4) void k_attn(
    const float* __restrict__ x, const u16* __restrict__ q_ws,
    const u16* __restrict__ k_ws, const u16* __restrict__ vt_ws,
    const float* __restrict__ gamma, float* __restrict__ out) {
  __shared__ u16 p_lds[2][64 * 64];     // 16 KB total

  const int bid = blockIdx.x;
  const int b = bid & 7;                // same-b blocks land on one XCD
  const int it = bid >> 3;
  const int i0 = it * 64;
  const int tid = threadIdx.x;
  const int w = tid >> 6, L = tid & 63; // 8 waves
  const int lr = L & 15, q4 = L >> 4;
  const int L31 = L & 31, Lhi = L >> 5, L7 = L & 7;
  const int isub = w & 3;               // S: i-subtile (16 rows)
  const int jh = w >> 2;                // S: j-half (2 of 4 subtiles)

  const short8 a_k = *(const short8*)(k_ws +
      ((size_t)(b * NTOK + i0 + isub * 16 + lr)) * CQK + q4 * 8);

  // V fragment base for this wave: group cg = w>>1, ct2 = w&1.
  const u16* vg = vt_ws +
      ((((size_t)b * 64) * 4 + (w >> 1)) * 8 + (w & 1)) * 512 + (size_t)L * 8;
  const u16* q_base = q_ws + (size_t)b * NTOK * CQK;

  f32x16 o_acc[2];                      // ih = 0,1 ; ch = w*32 + L31
#pragma unroll
  for (int ih = 0; ih < 2; ih++)
#pragma unroll
    for (int e = 0; e < 16; e++) o_acc[ih][e] = 0.f;
  float lsum = 0.f;

  // P write base offset: row i = isub*16+lr; half = (q4&1)^((i>>3)&1);
  // chunk XOR keyed on row&7 (= lr&7) as before.
  const int pw_off = (isub * 16 + lr) * 64 + (((q4 & 1) ^ ((lr >> 3) & 1)) << 2);
  const int q4h = q4 >> 1;
  u16* const pl0 = &p_lds[0][0];
  u16* const pl1 = &p_lds[1][0];

// exp(s) + packed b64 swizzled P-write for global j-subtile T into PW
#define EXPW(SV, T, PW)                                                          \
  do {                                                                           \
    const float p0 = fexp2((SV)[0]);                                             \
    const float p1 = fexp2((SV)[1]);                                             \
    const float p2 = fexp2((SV)[2]);                                             \
    const float p3 = fexp2((SV)[3]);                                             \
    lsum += (p0 + p1) + (p2 + p3);                                               \
    u32x2 pk;                                                                    \
    pk[0] = pack2(p0, p1);                                                       \
    pk[1] = pack2(p2, p3);                                                       \
    *(u32x2*)((PW) + (((2 * (T) + q4h) ^ (lr & 7)) * 8)) = pk;                   \
  } while (0)

  // --- prologue: Q(0)->bqA; V(0)->vV; S^T(0)+exp+P->pl0; Q(1)->bqB
  short8 bqA[2], bqB[2];
  short8 vV[4];
#pragma unroll
  for (int tt = 0; tt < 2; tt++)
    bqA[tt] = *(const short8*)(q_base +
        (size_t)((jh * 2 + tt) * 16 + lr) * CQK + q4 * 8);
#pragma unroll
  for (int ks = 0; ks < 4; ks++)
    vV[ks] = *(const short8*)(vg + (size_t)ks * 1024);
  {
    f32x4 s0 = MFMA16(bqA[0], a_k, ((f32x4){0.f, 0.f, 0.f, 0.f}));
    f32x4 s1 = MFMA16(bqA[1], a_k, ((f32x4){0.f, 0.f, 0.f, 0.f}));
    u16* pwn = pl0 + pw_off;
    EXPW(s0, jh * 2 + 0, pwn);
    EXPW(s1, jh * 2 + 1, pwn);
  }
#pragma unroll
  for (int tt = 0; tt < 2; tt++)
    bqB[tt] = *(const short8*)(q_base +
        (size_t)(64 + (jh * 2 + tt) * 16 + lr) * CQK + q4 * 8);

// One iteration: LDS-only barrier; S^T(JT+1) from BQN regs; Q(JT+2)->BQF;
// PV(JT) from PL_CUR + vV regs, with exp(JT+1)->PL_NXT and V(JT+1) reloads
// (into the just-freed vV slots) interleaved per ks.
#define ATTN_ITER(JT, PL_CUR, PL_NXT, BQN, BQF, DO_Q)                            \
  do {                                                                           \
    BAR_LDS(); /* all P(JT) writes visible; PL_NXT free for overwrite */         \
    f32x4 s0 = MFMA16(BQN[0], a_k, ((f32x4){0.f, 0.f, 0.f, 0.f}));               \
    f32x4 s1 = MFMA16(BQN[1], a_k, ((f32x4){0.f, 0.f, 0.f, 0.f}));               \
    if (DO_Q) {                                                                  \
      _Pragma("unroll")                                                          \
      for (int tt = 0; tt < 2; tt++)                                             \
        BQF[tt] = *(const short8*)(q_base +                                      \
            (size_t)((JT) * 64 + 128 + (jh * 2 + tt) * 16 + lr) * CQK + q4 * 8); \
    }                                                                            \
    u16* pwn = (PL_NXT) + pw_off;                                                \
    _Pragma("unroll")                                                            \
    for (int ks = 0; ks < 4; ks++) {                                             \
      const int slot = (((ks * 2 + Lhi) ^ L7)) * 8;                              \
      short8 a_p0 = *(const short8*)((PL_CUR) + L31 * 64 + slot);                \
      short8 a_p1 = *(const short8*)((PL_CUR) + (32 + L31) * 64 + slot);         \
      o_acc[0] = MFMA32(a_p0, vV[ks], o_acc[0]);                                 \
      o_acc[1] = MFMA32(a_p1, vV[ks], o_acc[1]);                                 \
      vV[ks] = *(const short8*)(vg +                                             \
          (size_t)((JT) + 1) * 16384 + ks * 1024);                               \
      if (ks == 0) EXPW(s0, jh * 2 + 0, pwn);                                    \
      if (ks == 2) EXPW(s1, jh * 2 + 1, pwn);                                    \
    }                                                                            \
  } while (0)

  for (int jt2 = 0; jt2 < 62; jt2 += 2) {
    ATTN_ITER(jt2,     pl0, pl1, bqB, bqA, 1);
    ATTN_ITER(jt2 + 1, pl1, pl0, bqA, bqB, 1);
  }
  // t=62: computes S(63)+P->pl1, loads V(63); no Q(64) prefetch.
  ATTN_ITER(62, pl0, pl1, bqB, bqA, 0);
#undef ATTN_ITER

  // t=63: PV only.
  BAR_LDS();
#pragma unroll
  for (int ks = 0; ks < 4; ks++) {
    const int slot = (((ks * 2 + Lhi) ^ L7)) * 8;
    short8 a_p0 = *(const short8*)(pl1 + L31 * 64 + slot);
    short8 a_p1 = *(const short8*)(pl1 + (32 + L31) * 64 + slot);
    o_acc[0] = MFMA32(a_p0, vV[ks], o_acc[0]);
    o_acc[1] = MFMA32(a_p1, vV[ks], o_acc[1]);
  }
#undef EXPW

  // softmax denominators: intra-wave reduce over q4, then merge the two
  // j-half partials (waves w and w+4 share rows isub*16+lr) via LDS.
  float s2 = lsum;
  s2 += __shfl_xor(s2, 16);
  s2 += __shfl_xor(s2, 32);
  BAR_LDS();
  float* lp = (float*)pl0;
  if (jh == 0 && q4 == 0) lp[isub * 16 + lr] = s2;
  BAR_LDS();
  if (jh == 1 && q4 == 0) lp[isub * 16 + lr] += s2;
  BAR_LDS();
  if (jh == 0 && q4 == 0) lp[isub * 16 + lr] = 1.0f / lp[isub * 16 + lr];
  BAR_LDS();

  float linv2[2][16];
#pragma unroll
  for (int ih = 0; ih < 2; ih++)
#pragma unroll
    for (int rg = 0; rg < 16; rg++)
      linv2[ih][rg] = lp[ih * 32 + (rg & 3) + 8 * (rg >> 2) + 4 * Lhi];

  const float g = gamma[0];
  const int c = w * 32 + L31;
#pragma unroll
  for (int ih = 0; ih < 2; ih++)
#pragma unroll
    for (int rg = 0; rg < 16; rg++) {
      const int i = i0 + ih * 32 + (rg & 3) + 8 * (rg >> 2) + 4 * Lhi;
      const size_t idx = ((size_t)(b * NTOK + i)) * CDIM + c;
      out[idx] = g * (o_acc[ih][rg] * linv2[ih][rg]) + x[idx];
    }
}

// ---------------------------------------------------------------------------
extern "C" void kernel_launch(void* const* d_in, const int* in_sizes, int n_in,
                              void* d_out, int out_size, void* d_ws, size_t ws_size,
                              hipStream_t stream) {
  const float* x  = (const float*)d_in[0];
  const float* Wq = (const float*)d_in[1];
  const float* bq = (const float*)d_in[2];
  const float* Wk = (const float*)d_in[3];
  const float* bk = (const float*)d_in[4];
  const float* Wv = (const float*)d_in[5];
  const float* bv = (const float*)d_in[6];
  const float* gamma = (const float*)d_in[7];
  float* out = (float*)d_out;

  char* ws = (char*)d_ws;
  u16* q_ws  = (u16*)(ws);
  u16* k_ws  = (u16*)(ws + (2u << 20));
  u16* vt_ws = (u16*)(ws + (4u << 20));
  u16* wtf   = (u16*)(ws + (20u << 20));
  float* bias = (float*)(ws + (20u << 20) + (256u << 10));

  k_prep<<<160, 64, 0, stream>>>(Wq, bq, Wk, bk, Wv, bv, wtf, bias);
  k_proj<<<512, 256, 0, stream>>>(x, wtf, bias, q_ws, k_ws, vt_ws);
  k_attn<<<512, 512, 0, stream>>>(x, q_ws, k_ws, vt_ws, gamma, out);
}